// Round 3
// baseline (192.247 us; speedup 1.0000x reference)
//
#include <hip/hip_runtime.h>
#include <hip/hip_bf16.h>
#include <math.h>

// Problem constants
#define S_LEN 16384
#define E_DIM 2048
#define H_DIM 1024
#define C_DIM 5

#define NB 512   // grid blocks (2 per CU guaranteed co-resident)
#define NT 256   // threads per block

// Software grid barrier: 4 barriers x 16 counters, each counter on its own
// 64B line to avoid same-line atomic serialization. Region = 4096 bytes.
#define NCTR 16
#define BAR_BYTES (4 * NCTR * 16 * 4)

__device__ __forceinline__ void gbar(int* bars, int k) {
  __syncthreads();
  if (threadIdx.x == 0) {
    __threadfence();  // make this block's writes visible device-wide
    int* ctr = bars + (k * NCTR + (blockIdx.x & (NCTR - 1))) * 16;
    __hip_atomic_fetch_add(ctr, 1, __ATOMIC_RELEASE, __HIP_MEMORY_SCOPE_AGENT);
    int done = 0;
    while (!done) {
      int s = 0;
#pragma unroll
      for (int i = 0; i < NCTR; ++i)
        s += __hip_atomic_load(bars + (k * NCTR + i) * 16, __ATOMIC_RELAXED,
                               __HIP_MEMORY_SCOPE_AGENT);
      done = (s == NB);
      if (!done) __builtin_amdgcn_s_sleep(8);
    }
    __threadfence();  // acquire: invalidate stale cached lines
  }
  __syncthreads();
}

__device__ __forceinline__ float wave_sum(float v) {
#pragma unroll
  for (int off = 32; off > 0; off >>= 1) v += __shfl_down(v, off);
  return v;
}

__device__ __forceinline__ float dot4(float4 a, float4 b) {
  return a.x * b.x + a.y * b.y + a.z * b.z + a.w * b.w;
}

// Fused LSTM layer: block b handles hidden units 2b, 2b+1. Wave w computes
// gate rows w*H + 2b (+1); thread 0/1 apply the cell nonlinearity.
// Deterministic fixed-order reductions throughout.
__device__ __forceinline__ void lstm_layer(
    const float4* __restrict__ w_ih, int xlen4,  // 512 (E) or 256 (H)
    const float4* __restrict__ w_hh,
    const float* __restrict__ b_ih, const float* __restrict__ b_hh,
    const float4* __restrict__ x, const float4* __restrict__ h,
    const float* __restrict__ c_prev, float* __restrict__ h_out,
    float* smemf) {
  int w = threadIdx.x >> 6;
  int lane = threadIdx.x & 63;
  int j0 = blockIdx.x * 2;
  int rowA = w * H_DIM + j0;

  float aA = 0.f, aB = 0.f;
  const float4* wiA = w_ih + (size_t)rowA * xlen4;
  const float4* wiB = wiA + xlen4;
#pragma unroll 4
  for (int k = lane; k < xlen4; k += 64) {
    float4 xv = x[k];
    float4 wa = wiA[k];
    float4 wb = wiB[k];
    aA += dot4(wa, xv);
    aB += dot4(wb, xv);
  }
  const float4* whA = w_hh + (size_t)rowA * 256;
  const float4* whB = whA + 256;
#pragma unroll 4
  for (int k = lane; k < 256; k += 64) {
    float4 hv = h[k];
    float4 wa = whA[k];
    float4 wb = whB[k];
    aA += dot4(wa, hv);
    aB += dot4(wb, hv);
  }
  aA = wave_sum(aA);
  aB = wave_sum(aB);
  if (lane == 0) {
    smemf[w * 2 + 0] = aA + b_ih[rowA] + b_hh[rowA];
    smemf[w * 2 + 1] = aB + b_ih[rowA + 1] + b_hh[rowA + 1];
  }
  __syncthreads();
  if (threadIdx.x < 2) {
    int j = j0 + threadIdx.x;
    float ig = smemf[0 + threadIdx.x];
    float fg = smemf[2 + threadIdx.x];
    float gg = smemf[4 + threadIdx.x];
    float og = smemf[6 + threadIdx.x];
    float si = 1.f / (1.f + expf(-ig));
    float sf = 1.f / (1.f + expf(-fg));
    float so = 1.f / (1.f + expf(-og));
    float c2 = sf * c_prev[j] + si * tanhf(gg);
    h_out[j] = so * tanhf(c2);
  }
}

__global__ __launch_bounds__(NT, 2) void decoder_mega_k(
    const float* __restrict__ enc,
    const float* __restrict__ hidden, const float* __restrict__ c_in,
    const float* __restrict__ w_ih_l0, const float* __restrict__ w_hh_l0,
    const float* __restrict__ b_ih_l0, const float* __restrict__ b_hh_l0,
    const float* __restrict__ w_ih_l1, const float* __restrict__ w_hh_l1,
    const float* __restrict__ b_ih_l1, const float* __restrict__ b_hh_l1,
    const float* __restrict__ fc_w, const float* __restrict__ fc_b,
    int* __restrict__ bars, float* __restrict__ part,
    float* __restrict__ colsum, float* __restrict__ h1,
    float* __restrict__ h2, float* __restrict__ out) {
  __shared__ float4 smem4[NT];
  float* smemf = (float*)smem4;

  // ---- Phase A: colsum partials. 64 row-groups x 8 col-blocks.
  {
    const float4* enc4 = (const float4*)enc;
    int g = blockIdx.x >> 3;         // 0..63: rows g*256 .. g*256+255
    int cb = blockIdx.x & 7;         // 0..7: f4-cols cb*64 .. cb*64+63
    int sub = threadIdx.x >> 6;      // 0..3: 64-row strip
    int lane = threadIdx.x & 63;
    int c4 = cb * 64 + lane;         // 0..511
    size_t base = ((size_t)(g * 256 + sub * 64)) * 512 + c4;
    float4 acc = {0.f, 0.f, 0.f, 0.f};
#pragma unroll 8
    for (int r = 0; r < 64; ++r) {
      float4 v = enc4[base + (size_t)r * 512];
      acc.x += v.x; acc.y += v.y; acc.z += v.z; acc.w += v.w;
    }
    smem4[threadIdx.x] = acc;
    __syncthreads();
    if (threadIdx.x < 64) {
      float4 a = smem4[threadIdx.x];
      float4 b = smem4[64 + threadIdx.x];
      float4 c = smem4[128 + threadIdx.x];
      float4 d = smem4[192 + threadIdx.x];
      float4 s;
      s.x = (a.x + b.x) + (c.x + d.x);
      s.y = (a.y + b.y) + (c.y + d.y);
      s.z = (a.z + b.z) + (c.z + d.z);
      s.w = (a.w + b.w) + (c.w + d.w);
      ((float4*)part)[(size_t)g * 512 + cb * 64 + threadIdx.x] = s;
    }
  }
  gbar(bars, 0);

  // ---- Phase B: reduce 64 partials -> colsum (blocks 0..7, 1 thread/col).
  if (blockIdx.x < 8) {
    int col = blockIdx.x * NT + threadIdx.x;  // 0..2047
    float s = 0.f;
#pragma unroll 8
    for (int g = 0; g < 64; ++g) s += part[(size_t)g * E_DIM + col];
    colsum[col] = s;
  }
  gbar(bars, 1);

  // ---- Phase C: LSTM layer 0 (x = colsum, h = hidden[0], c = c[0]) -> h1
  lstm_layer((const float4*)w_ih_l0, E_DIM / 4, (const float4*)w_hh_l0,
             b_ih_l0, b_hh_l0, (const float4*)colsum, (const float4*)hidden,
             c_in, h1, smemf);
  gbar(bars, 2);

  // ---- Phase D: LSTM layer 1 (x = h1, h = hidden[1], c = c[1]) -> h2
  lstm_layer((const float4*)w_ih_l1, H_DIM / 4, (const float4*)w_hh_l1,
             b_ih_l1, b_hh_l1, (const float4*)h1,
             (const float4*)(hidden + H_DIM), c_in + H_DIM, h2, smemf);
  gbar(bars, 3);

  // ---- Phase E: FC (block 0 only): out[r] = fc_w[r,:] . h2 + fc_b[r]
  if (blockIdx.x == 0) {
    int w = threadIdx.x >> 6;
    int lane = threadIdx.x & 63;
    const float4* h24 = (const float4*)h2;
    for (int r = w; r < C_DIM; r += 4) {
      const float4* wr4 = (const float4*)fc_w + (size_t)r * 256;
      float a = 0.f;
#pragma unroll 4
      for (int k = lane; k < 256; k += 64) a += dot4(wr4[k], h24[k]);
      a = wave_sum(a);
      if (lane == 0) out[r] = a + fc_b[r];
    }
  }
}

// ---------------------------------------------------------------------------
extern "C" void kernel_launch(void* const* d_in, const int* in_sizes, int n_in,
                              void* d_out, int out_size, void* d_ws, size_t ws_size,
                              hipStream_t stream) {
  const float* enc     = (const float*)d_in[0];   // (S,1,E)
  const float* hidden  = (const float*)d_in[1];   // (2,1,H)
  const float* c_in    = (const float*)d_in[2];   // (2,1,H)
  // d_in[3] attn_w, d_in[4] attn_b: dead (softmax over size-1 axis == 1)
  const float* w_ih_l0 = (const float*)d_in[5];   // (4H, E)
  const float* w_hh_l0 = (const float*)d_in[6];   // (4H, H)
  const float* b_ih_l0 = (const float*)d_in[7];
  const float* b_hh_l0 = (const float*)d_in[8];
  const float* w_ih_l1 = (const float*)d_in[9];   // (4H, H)
  const float* w_hh_l1 = (const float*)d_in[10];  // (4H, H)
  const float* b_ih_l1 = (const float*)d_in[11];
  const float* b_hh_l1 = (const float*)d_in[12];
  const float* fc_w    = (const float*)d_in[13];  // (C, H)
  const float* fc_b    = (const float*)d_in[14];

  int* bars = (int*)d_ws;
  float* fws = (float*)((char*)d_ws + 4096);
  float* part   = fws;                  // 64 * 2048 floats (512 KB)
  float* colsum = part + 64 * E_DIM;    // 2048
  float* h1     = colsum + E_DIM;       // 1024
  float* h2     = h1 + H_DIM;           // 1024
  float* out    = (float*)d_out;

  // zero the barrier counters (graph-capture-legal async memset)
  hipMemsetAsync(d_ws, 0, BAR_BYTES, stream);

  decoder_mega_k<<<NB, NT, 0, stream>>>(
      enc, hidden, c_in, w_ih_l0, w_hh_l0, b_ih_l0, b_hh_l0,
      w_ih_l1, w_hh_l1, b_ih_l1, b_hh_l1, fc_w, fc_b,
      bars, part, colsum, h1, h2, out);
}

// Round 4
// 55.396 us; speedup vs baseline: 3.4704x; 3.4704x over previous
//
#include <hip/hip_runtime.h>
#include <hip/hip_bf16.h>
#include <math.h>

// Problem constants
#define S_LEN 16384
#define E_DIM 2048
#define H_DIM 1024
#define G_DIM 4096   // 4*H
#define C_DIM 5

// Column-sum geometry: 1024 blocks = 2 col-halves x 512 chunks x 32 rows.
#define CS_CHUNKS 512
#define CS_ROWS   (S_LEN / CS_CHUNKS)   // 32

// workspace layout (float offsets)
#define WS_PART   0                              // CS_CHUNKS*E_DIM = 1M floats (4 MB)
#define WS_COLSUM (WS_PART + CS_CHUNKS * E_DIM)  // 2048
#define WS_G0     (WS_COLSUM + E_DIM)            // 4096
#define WS_G1     (WS_G0 + G_DIM)                // 4096

__device__ __forceinline__ float wave_sum(float v) {
#pragma unroll
  for (int off = 32; off > 0; off >>= 1) v += __shfl_down(v, off);
  return v;
}

__device__ __forceinline__ float dot4(float4 a, float4 b) {
  return a.x * b.x + a.y * b.y + a.z * b.z + a.w * b.w;
}

__device__ __forceinline__ float sigm(float x) { return 1.f / (1.f + expf(-x)); }

// ---------------------------------------------------------------------------
// Phase 1: per-chunk partial column sums of encoder_hiddens (S x E).
// grid = 2 col-halves x 512 chunks = 1024 blocks (4/CU), 256 threads, float4.
__global__ __launch_bounds__(256) void colsum_partial_k(
    const float4* __restrict__ enc, float4* __restrict__ part) {
  const int E4 = E_DIM / 4;  // 512
  int colgroup = blockIdx.x & 1;
  int chunk = blockIdx.x >> 1;
  int e4 = colgroup * 256 + threadIdx.x;  // 0..511
  float4 acc = {0.f, 0.f, 0.f, 0.f};
  size_t base = (size_t)chunk * CS_ROWS * E4 + e4;
#pragma unroll 8
  for (int r = 0; r < CS_ROWS; ++r) {
    float4 v = enc[base + (size_t)r * E4];
    acc.x += v.x; acc.y += v.y; acc.z += v.z; acc.w += v.w;
  }
  part[(size_t)chunk * E4 + e4] = acc;
}

// Phase 2: reduce CS_CHUNKS partials -> colsum. 32 blocks x 256 threads.
// Block b covers float-cols [64b, 64b+64); 4 chunk-groups of 128, fixed-order
// LDS combine -> deterministic.
__global__ __launch_bounds__(256) void colsum_final_k(
    const float* __restrict__ part, float* __restrict__ colsum) {
  __shared__ float red[4][64];
  int lane = threadIdx.x & 63;
  int grp = threadIdx.x >> 6;           // 0..3
  int col = blockIdx.x * 64 + lane;     // 0..2047
  float acc = 0.f;
  int c0 = grp * (CS_CHUNKS / 4);
#pragma unroll 8
  for (int ch = c0; ch < c0 + CS_CHUNKS / 4; ++ch)
    acc += part[(size_t)ch * E_DIM + col];
  red[grp][lane] = acc;
  __syncthreads();
  if (threadIdx.x < 64) {
    float s = (red[0][lane] + red[1][lane]) + (red[2][lane] + red[3][lane]);
    colsum[col] = s;
  }
}

// ---------------------------------------------------------------------------
// LSTM layer-0 gate matvec: row = 4*blockIdx + wave; x = colsum (E), h = h0.
__global__ __launch_bounds__(256) void gates0_k(
    const float4* __restrict__ w_ih, const float4* __restrict__ w_hh,
    const float* __restrict__ b_ih, const float* __restrict__ b_hh,
    const float4* __restrict__ x, const float4* __restrict__ h,
    float* __restrict__ gates) {
  int wave = threadIdx.x >> 6;
  int lane = threadIdx.x & 63;
  int row = blockIdx.x * 4 + wave;  // < 4096

  float acc = 0.f;
  const float4* wi = w_ih + (size_t)row * 512;
#pragma unroll
  for (int k = lane; k < 512; k += 64) acc += dot4(wi[k], x[k]);
  const float4* wh = w_hh + (size_t)row * 256;
#pragma unroll
  for (int k = lane; k < 256; k += 64) acc += dot4(wh[k], h[k]);
  acc = wave_sum(acc);
  if (lane == 0) gates[row] = acc + b_ih[row] + b_hh[row];
}

// ---------------------------------------------------------------------------
// LSTM layer-1 gates with cell-0 fused in the prologue: every block computes
// h1 (from g0, c0) into LDS, then does its 4 gate-row matvecs against it.
__global__ __launch_bounds__(256) void gates1_cell0_k(
    const float* __restrict__ g0, const float* __restrict__ c0,
    const float4* __restrict__ w_ih, const float4* __restrict__ w_hh,
    const float* __restrict__ b_ih, const float* __restrict__ b_hh,
    const float4* __restrict__ h,   // hidden[1]
    float* __restrict__ gates) {
  __shared__ __align__(16) float h1s[H_DIM];
  // prologue: cell 0 (fixed arithmetic, redundant per block — 16 KB L2 reads)
#pragma unroll
  for (int k = 0; k < 4; ++k) {
    int j = threadIdx.x + 256 * k;
    float ig = g0[j], fg = g0[H_DIM + j], gg = g0[2 * H_DIM + j],
          og = g0[3 * H_DIM + j];
    float c2 = sigm(fg) * c0[j] + sigm(ig) * tanhf(gg);
    h1s[j] = sigm(og) * tanhf(c2);
  }
  __syncthreads();

  int wave = threadIdx.x >> 6;
  int lane = threadIdx.x & 63;
  int row = blockIdx.x * 4 + wave;  // < 4096
  const float4* h1s4 = (const float4*)h1s;

  float acc = 0.f;
  const float4* wi = w_ih + (size_t)row * 256;
#pragma unroll
  for (int k = lane; k < 256; k += 64) acc += dot4(wi[k], h1s4[k]);
  const float4* wh = w_hh + (size_t)row * 256;
#pragma unroll
  for (int k = lane; k < 256; k += 64) acc += dot4(wh[k], h[k]);
  acc = wave_sum(acc);
  if (lane == 0) gates[row] = acc + b_ih[row] + b_hh[row];
}

// ---------------------------------------------------------------------------
// Final: cell-1 in prologue (h2 into LDS), then out[r] = fc_w[r,:].h2 + fc_b.
__global__ __launch_bounds__(512) void fc_cell1_k(
    const float* __restrict__ g1, const float* __restrict__ c1,
    const float4* __restrict__ fc_w, const float* __restrict__ fc_b,
    float* __restrict__ out) {
  __shared__ __align__(16) float h2s[H_DIM];
#pragma unroll
  for (int k = 0; k < 2; ++k) {
    int j = threadIdx.x + 512 * k;
    float ig = g1[j], fg = g1[H_DIM + j], gg = g1[2 * H_DIM + j],
          og = g1[3 * H_DIM + j];
    float c2 = sigm(fg) * c1[j] + sigm(ig) * tanhf(gg);
    h2s[j] = sigm(og) * tanhf(c2);
  }
  __syncthreads();

  int wave = threadIdx.x >> 6;  // 0..7
  int lane = threadIdx.x & 63;
  if (wave < C_DIM) {
    const float4* h24 = (const float4*)h2s;
    const float4* wr = fc_w + (size_t)wave * 256;
    float acc = 0.f;
#pragma unroll
    for (int k = lane; k < 256; k += 64) acc += dot4(wr[k], h24[k]);
    acc = wave_sum(acc);
    if (lane == 0) out[wave] = acc + fc_b[wave];
  }
}

// ---------------------------------------------------------------------------
extern "C" void kernel_launch(void* const* d_in, const int* in_sizes, int n_in,
                              void* d_out, int out_size, void* d_ws, size_t ws_size,
                              hipStream_t stream) {
  const float* enc     = (const float*)d_in[0];   // (S,1,E)
  const float* hidden  = (const float*)d_in[1];   // (2,1,H)
  const float* c_in    = (const float*)d_in[2];   // (2,1,H)
  // d_in[3] attn_w, d_in[4] attn_b: dead (softmax over size-1 axis == 1)
  const float* w_ih_l0 = (const float*)d_in[5];   // (4H, E)
  const float* w_hh_l0 = (const float*)d_in[6];   // (4H, H)
  const float* b_ih_l0 = (const float*)d_in[7];
  const float* b_hh_l0 = (const float*)d_in[8];
  const float* w_ih_l1 = (const float*)d_in[9];   // (4H, H)
  const float* w_hh_l1 = (const float*)d_in[10];  // (4H, H)
  const float* b_ih_l1 = (const float*)d_in[11];
  const float* b_hh_l1 = (const float*)d_in[12];
  const float* fc_w    = (const float*)d_in[13];  // (C, H)
  const float* fc_b    = (const float*)d_in[14];

  float* ws = (float*)d_ws;
  float* part   = ws + WS_PART;
  float* colsum = ws + WS_COLSUM;
  float* g0     = ws + WS_G0;
  float* g1     = ws + WS_G1;
  float* out    = (float*)d_out;

  // 1. attn_applied = column sum of enc (softmax over size-1 axis == 1)
  colsum_partial_k<<<2 * CS_CHUNKS, 256, 0, stream>>>(
      (const float4*)enc, (float4*)part);
  colsum_final_k<<<E_DIM / 64, 256, 0, stream>>>(part, colsum);

  // 2. LSTM layer-0 gates
  gates0_k<<<G_DIM / 4, 256, 0, stream>>>(
      (const float4*)w_ih_l0, (const float4*)w_hh_l0, b_ih_l0, b_hh_l0,
      (const float4*)colsum, (const float4*)hidden, g0);

  // 3. cell-0 (fused) + LSTM layer-1 gates
  gates1_cell0_k<<<G_DIM / 4, 256, 0, stream>>>(
      g0, c_in,
      (const float4*)w_ih_l1, (const float4*)w_hh_l1, b_ih_l1, b_hh_l1,
      (const float4*)(hidden + H_DIM), g1);

  // 4. cell-1 (fused) + FC
  fc_cell1_k<<<1, 512, 0, stream>>>(
      g1, c_in + H_DIM, (const float4*)fc_w, fc_b, out);
}